// Round 15
// baseline (181.411 us; speedup 1.0000x reference)
//
#include <hip/hip_runtime.h>

#define S_LEN 2048
#define D_MODEL 1024
#define DH 64      // head dim
#define BQ 128     // q rows per block (32 per wave)
#define BK 128     // keys per k-tile
#define ZSCALE 0.18033688f   // 0.125 * log2(e) — folded into Q fragments

using short8 = __attribute__((ext_vector_type(8))) short;
using s4v    = __attribute__((ext_vector_type(4))) short;
using f32x4  = __attribute__((ext_vector_type(4))) float;
using u32x4  = __attribute__((ext_vector_type(4))) unsigned int;

#define BMM(a, b, c) __builtin_amdgcn_mfma_f32_16x16x32_bf16((a), (b), (c), 0, 0, 0)

__device__ __forceinline__ unsigned short f2bf(float x) {
    union { float f; unsigned int u; } c; c.f = x;
    unsigned int u = c.u;
    u += 0x7fffu + ((u >> 16) & 1u);   // RNE
    return (unsigned short)(u >> 16);
}

// ---- fused converter (verified) ----
__global__ __launch_bounds__(256) void cvt_fused(const float* __restrict__ V,
                                                 const int* __restrict__ M,
                                                 const float* __restrict__ K,
                                                 unsigned short* __restrict__ VT,
                                                 unsigned long long* __restrict__ Mb,
                                                 unsigned short* __restrict__ KB) {
    const int blk = blockIdx.x;
    const int tid = threadIdx.x;
    if (blk < 1024) {
        __shared__ float tsF[64][65];
        const int b  = blk >> 9;
        const int h  = (blk >> 5) & 15;
        const int s0 = (blk & 31) * 64;
        #pragma unroll
        for (int it = 0; it < 2; ++it) {
            int seg = tid + it * 256;
            int s = seg >> 3, d8 = (seg & 7) << 3;
            const float* p = V + (size_t)(b * S_LEN + s0 + s) * D_MODEL + h * DH + d8;
            f32x4 a = *(const f32x4*)p;
            f32x4 c = *(const f32x4*)(p + 4);
            #pragma unroll
            for (int j = 0; j < 4; ++j) { tsF[s][d8 + j] = a[j]; tsF[s][d8 + 4 + j] = c[j]; }
        }
        __syncthreads();
        #pragma unroll
        for (int it = 0; it < 2; ++it) {
            int seg = tid + it * 256;
            int d = seg >> 3, s8 = (seg & 7) << 3;
            short8 w;
            #pragma unroll
            for (int j = 0; j < 8; ++j) w[j] = (short)f2bf(tsF[s8 + j][d]);
            *(short8*)(VT + ((size_t)((b * 16 + h) * 64 + d)) * S_LEN + s0 + s8) = w;
        }
    } else if (blk < 2048) {
        const int pb   = blk - 1024;
        const int wave = tid >> 6, lane = tid & 63;
        const int row  = pb * 4 + wave;
        const int* mp  = M + (size_t)row * S_LEN;
        #pragma unroll 4
        for (int it = 0; it < 32; ++it) {
            int m = mp[it * 64 + lane];
            unsigned long long bal = __ballot(m != 0);
            if (lane == 0) Mb[(size_t)row * 32 + it] = bal;
        }
    } else {
        size_t base = (size_t)(blk - 2048) * 4096;
        #pragma unroll
        for (int it = 0; it < 4; ++it) {
            size_t i = base + ((size_t)(it * 256 + tid)) * 4;
            f32x4 a = *(const f32x4*)(K + i);
            s4v w;
            #pragma unroll
            for (int j = 0; j < 4; ++j) w[j] = (short)f2bf(a[j]);
            *(s4v*)(KB + i) = w;
        }
    }
}

// ---- main kernel v18 = v15 body (verified: swizzled LDS, 0 conflicts,
//      interleaved QK/PV, T14 prefetch) generalized to SPLIT-K:
//      split_mode=1: grid 1024, each block does HALF the key range (8 tiles)
//      and writes raw partial sums (PO: Sum p*V, PL: Sum p) — exact because the
//      softmax is max-free.  4 blocks/CU co-resident -> 4 waves/SIMD (2x TLP).
//      split_mode=0: grid 512, divide in epilogue, write O directly (v15).
__global__ __launch_bounds__(256) void mha_fwd_v18(
    const float* __restrict__ Q,
    const float* __restrict__ K,             // f32 (used when KB == 0)
    const unsigned short* __restrict__ KB,   // bf16 preconverted (may be null)
    const unsigned short* __restrict__ VT,   // bf16 pre-transposed [d][s]
    const unsigned long long* __restrict__ Mb, // packed mask u64, 32/row
    float* __restrict__ O,
    float* __restrict__ PO,                  // partials (may be null)
    float* __restrict__ PL,
    int kbf, int split_mode)
{
    __shared__ alignas(16) unsigned short Ks[BK][64];   // 16 KB
    __shared__ alignas(16) unsigned short Vt[DH][128];  // 16 KB

    // XCD-chunked swizzle
    const int blk0 = blockIdx.x;
    int blk, b, h, qt, split;
    if (split_mode) {
        blk = ((blk0 & 7) << 7) | (blk0 >> 3);          // nwg=1024, chunk 128
        b = blk >> 9; h = (blk >> 5) & 15; qt = (blk >> 1) & 15; split = blk & 1;
    } else {
        blk = ((blk0 & 7) << 6) | (blk0 >> 3);          // nwg=512, chunk 64
        b = blk >> 8; h = (blk >> 4) & 15; qt = blk & 15; split = 0;
    }
    const int qbase = qt * BQ;
    const int bh  = b * 16 + h;
    const int kb0 = split * (S_LEN / 2);
    const int kbend = split_mode ? kb0 + S_LEN / 2 : S_LEN;

    const int tid  = threadIdx.x;
    const int wave = tid >> 6;
    const int lane = tid & 63;
    const int n16  = lane & 15;
    const int quad = lane >> 4;
    const int bq   = quad << 3;          // mask half-word shift
    const int n7   = n16 & 7;

    const int srow = tid >> 3;
    const int prow = (((srow >> 2) & 1) << 4) | (((srow >> 3) & 3) << 2) | (srow & 3);
    const int vrow = tid >> 4;

    // LDS XOR-swizzle columns (16B granules; phys = logical ^ (row & (ng-1)))
    const int kwcol = (((tid & 7) ^ (prow & 7)) << 3);
    const int vwcol = (((tid & 15) ^ vrow) << 3);
    const int krc0  = ((quad ^ n7) << 3);
    const int krc1  = krc0 ^ 32;
    int vrc[4];
    #pragma unroll
    for (int kc = 0; kc < 4; ++kc) vrc[kc] = (((kc * 4 + quad) ^ n16) << 3);

    // Q fragments (B operand), PRE-SCALED by ZSCALE
    short8 qf[2][2];
    #pragma unroll
    for (int qg = 0; qg < 2; ++qg) {
        const size_t qoff = (size_t)(b * S_LEN + qbase + wave * 32 + qg * 16 + n16) * D_MODEL
                          + h * DH + quad * 8;
        f32x4 a0 = *(const f32x4*)(Q + qoff);
        f32x4 a1 = *(const f32x4*)(Q + qoff + 4);
        f32x4 a2 = *(const f32x4*)(Q + qoff + 32);
        f32x4 a3 = *(const f32x4*)(Q + qoff + 36);
        short8 q0, q1;
        #pragma unroll
        for (int j = 0; j < 4; ++j) {
            q0[j] = (short)f2bf(a0[j] * ZSCALE); q0[4 + j] = (short)f2bf(a1[j] * ZSCALE);
            q1[j] = (short)f2bf(a2[j] * ZSCALE); q1[4 + j] = (short)f2bf(a3[j] * ZSCALE);
        }
        qf[qg][0] = q0; qf[qg][1] = q1;
    }

    const short8 ones = {0x3F80,0x3F80,0x3F80,0x3F80,0x3F80,0x3F80,0x3F80,0x3F80}; // bf16 1.0

    f32x4 o[2][4], o4[2];
    #pragma unroll
    for (int qg = 0; qg < 2; ++qg) {
        #pragma unroll
        for (int dg = 0; dg < 4; ++dg) o[qg][dg] = f32x4{0.f,0.f,0.f,0.f};
        o4[qg] = f32x4{0.f,0.f,0.f,0.f};
    }

    const unsigned long long* mrow[2];
    #pragma unroll
    for (int qg = 0; qg < 2; ++qg)
        mrow[qg] = Mb + (size_t)(b * S_LEN + qbase + wave * 32 + qg * 16 + n16) * 32;

    const size_t kbase = (size_t)(b * S_LEN) * D_MODEL + h * DH;
    const size_t vbase = (size_t)(bh * 64) * S_LEN;

    // ---- prologue: prefetch tile kb0 into regs ----
    short8 ka[4], va[4];
    unsigned long long mw[2][2];
    if (kbf) {
        #pragma unroll
        for (int i = 0; i < 4; ++i)
            ka[i] = *(const short8*)(KB + kbase + (size_t)(kb0 + i * 32 + srow) * D_MODEL + ((tid & 7) << 3));
    } else {
        #pragma unroll
        for (int i = 0; i < 4; ++i) {
            const float* kp = K + kbase + (size_t)(kb0 + i * 32 + srow) * D_MODEL + ((tid & 7) << 3);
            f32x4 p0 = *(const f32x4*)kp, p1 = *(const f32x4*)(kp + 4);
            short8 w;
            #pragma unroll
            for (int j = 0; j < 4; ++j) { w[j] = (short)f2bf(p0[j]); w[4 + j] = (short)f2bf(p1[j]); }
            ka[i] = w;
        }
    }
    #pragma unroll
    for (int i = 0; i < 4; ++i)   // VT is [d][s]: tile offset on the COLUMN
        va[i] = *(const short8*)(VT + vbase + (size_t)(vrow + 16 * i) * S_LEN + kb0 + ((tid & 15) << 3));
    {
        const int wi = kb0 >> 6;
        #pragma unroll
        for (int qg = 0; qg < 2; ++qg) { mw[qg][0] = mrow[qg][wi]; mw[qg][1] = mrow[qg][wi + 1]; }
    }

    for (int kb = kb0; kb < kbend; kb += BK) {
        // barrier 1: all waves done READING prev tile; raw (no vmcnt drain)
        __builtin_amdgcn_s_barrier();
        __builtin_amdgcn_sched_barrier(0);

        // stage tile (swizzled columns; sigma-permuted K rows)
        #pragma unroll
        for (int i = 0; i < 4; ++i) {
            *(short8*)&Ks[prow + 32 * i][kwcol] = ka[i];
            *(short8*)&Vt[vrow + 16 * i][vwcol] = va[i];
        }

        // issue next tile's loads — consumed by NEXT iteration's ds_writes
        const int kn = kb + BK;
        const bool more = kn < kbend;
        short8 nka[4], nva[4];
        unsigned long long nmw[2][2];
        if (more) {
            if (kbf) {
                #pragma unroll
                for (int i = 0; i < 4; ++i)
                    nka[i] = *(const short8*)(KB + kbase + (size_t)(kn + i * 32 + srow) * D_MODEL + ((tid & 7) << 3));
            } else {
                #pragma unroll
                for (int i = 0; i < 4; ++i) {
                    const float* kp = K + kbase + (size_t)(kn + i * 32 + srow) * D_MODEL + ((tid & 7) << 3);
                    f32x4 p0 = *(const f32x4*)kp, p1 = *(const f32x4*)(kp + 4);
                    short8 w;
                    #pragma unroll
                    for (int j = 0; j < 4; ++j) { w[j] = (short)f2bf(p0[j]); w[4 + j] = (short)f2bf(p1[j]); }
                    nka[i] = w;
                }
            }
            #pragma unroll
            for (int i = 0; i < 4; ++i)
                nva[i] = *(const short8*)(VT + vbase + (size_t)(vrow + 16 * i) * S_LEN + kn + ((tid & 15) << 3));
            const int wi = kn >> 6;
            #pragma unroll
            for (int qg = 0; qg < 2; ++qg) { nmw[qg][0] = mrow[qg][wi]; nmw[qg][1] = mrow[qg][wi + 1]; }
        }

        // mask half-words (register-only; off the post-barrier path)
        unsigned int am[2][4];
        #pragma unroll
        for (int qg = 0; qg < 2; ++qg) {
            am[qg][0] = ((unsigned int)mw[qg][0]) >> bq;
            am[qg][1] = ((unsigned int)(mw[qg][0] >> 32)) >> bq;
            am[qg][2] = ((unsigned int)mw[qg][1]) >> bq;
            am[qg][3] = ((unsigned int)(mw[qg][1] >> 32)) >> bq;
        }

        // barrier 2: my LDS writes committed (lgkm only), then all waves sync
        asm volatile("s_waitcnt lgkmcnt(0)" ::: "memory");
        __builtin_amdgcn_s_barrier();
        __builtin_amdgcn_sched_barrier(0);

        // ---- interleaved compute: PV[kc] fires right after its two QK cts ----
        u32x4 Af[2][4];   // [qg][kc]
        auto QKCT = [&](int ct) {
            short8 kf0 = *(const short8*)&Ks[ct * 16 + n16][krc0];
            short8 kf1 = *(const short8*)&Ks[ct * 16 + n16][krc1];
            f32x4 sA = {0.f,0.f,0.f,0.f}, sB = sA;
            sA = BMM(kf0, qf[0][0], sA); sA = BMM(kf1, qf[0][1], sA);
            sB = BMM(kf0, qf[1][0], sB); sB = BMM(kf1, qf[1][1], sB);
            unsigned int puA[4], puB[4];
            #pragma unroll
            for (int r = 0; r < 4; ++r) {
                puA[r] = __float_as_uint(__builtin_amdgcn_exp2f(sA[r]));
                puB[r] = __float_as_uint(__builtin_amdgcn_exp2f(sB[r]));
            }
            const int sel = ct >> 1, sb = (ct & 1) * 4, kc = ct >> 1, ub = (ct & 1) * 2;
            unsigned int nibA = (am[0][sel] >> sb) & 0xFu;
            unsigned int nibB = (am[1][sel] >> sb) & 0xFu;
            unsigned int m8A = ((nibA * 0x00204081u) & 0x01010101u) * 0xFFu;
            unsigned int m8B = ((nibB * 0x00204081u) & 0x01010101u) * 0xFFu;
            Af[0][kc][ub + 0] = __builtin_amdgcn_perm(puA[1], puA[0], 0x07060302u)
                              & __builtin_amdgcn_perm(0u, m8A, 0x01010000u);
            Af[0][kc][ub + 1] = __builtin_amdgcn_perm(puA[3], puA[2], 0x07060302u)
                              & __builtin_amdgcn_perm(0u, m8A, 0x03030202u);
            Af[1][kc][ub + 0] = __builtin_amdgcn_perm(puB[1], puB[0], 0x07060302u)
                              & __builtin_amdgcn_perm(0u, m8B, 0x01010000u);
            Af[1][kc][ub + 1] = __builtin_amdgcn_perm(puB[3], puB[2], 0x07060302u)
                              & __builtin_amdgcn_perm(0u, m8B, 0x03030202u);
        };
        auto PVKC = [&](int kc) {
            short8 v0 = *(const short8*)&Vt[      n16][vrc[kc]];
            short8 v1 = *(const short8*)&Vt[16 + n16][vrc[kc]];
            short8 v2 = *(const short8*)&Vt[32 + n16][vrc[kc]];
            short8 v3 = *(const short8*)&Vt[48 + n16][vrc[kc]];
            union { u32x4 u; short8 s; } c0, c1;
            c0.u = Af[0][kc]; c1.u = Af[1][kc];
            o[0][0] = BMM(c0.s, v0, o[0][0]); o[0][1] = BMM(c0.s, v1, o[0][1]);
            o[0][2] = BMM(c0.s, v2, o[0][2]); o[0][3] = BMM(c0.s, v3, o[0][3]);
            o4[0]   = BMM(c0.s, ones, o4[0]);
            o[1][0] = BMM(c1.s, v0, o[1][0]); o[1][1] = BMM(c1.s, v1, o[1][1]);
            o[1][2] = BMM(c1.s, v2, o[1][2]); o[1][3] = BMM(c1.s, v3, o[1][3]);
            o4[1]   = BMM(c1.s, ones, o4[1]);
        };

        __builtin_amdgcn_s_setprio(1);
        QKCT(0); QKCT(1);
        PVKC(0);
        QKCT(2); QKCT(3);
        PVKC(1);
        QKCT(4); QKCT(5);
        PVKC(2);
        QKCT(6); QKCT(7);
        PVKC(3);
        __builtin_amdgcn_s_setprio(0);

        if (more) {
            #pragma unroll
            for (int i = 0; i < 4; ++i) { ka[i] = nka[i]; va[i] = nva[i]; }
            #pragma unroll
            for (int qg = 0; qg < 2; ++qg) { mw[qg][0] = nmw[qg][0]; mw[qg][1] = nmw[qg][1]; }
        }
    }

    if (PO) {
        // split epilogue: write raw partials (no divide); exact combine later
        const int pblk = (bh * 16 + qt) * 2 + split;
        float* pp = PO + (size_t)pblk * (BQ * DH);
        float* pl = PL + (size_t)pblk * BQ;
        #pragma unroll
        for (int qg = 0; qg < 2; ++qg) {
            #pragma unroll
            for (int r = 0; r < 4; ++r) {
                const int rowin = wave * 32 + qg * 16 + quad * 4 + r;
                float* op = pp + rowin * DH + n16;
                op[0]  = o[qg][0][r];
                op[16] = o[qg][1][r];
                op[32] = o[qg][2][r];
                op[48] = o[qg][3][r];
                if (n16 == 0) pl[rowin] = o4[qg][r];
            }
        }
    } else {
        // unsplit epilogue: normalize and store f32
        #pragma unroll
        for (int qg = 0; qg < 2; ++qg) {
            #pragma unroll
            for (int r = 0; r < 4; ++r) {
                float rl = 1.f / o4[qg][r];
                size_t row = (size_t)(b * S_LEN + qbase + wave * 32 + qg * 16 + quad * 4 + r);
                float* op = O + row * D_MODEL + h * DH + n16;
                op[0]  = o[qg][0][r] * rl;
                op[16] = o[qg][1][r] * rl;
                op[32] = o[qg][2][r] * rl;
                op[48] = o[qg][3][r] * rl;
            }
        }
    }
}

// ---- combine: O = (PO[0]+PO[1]) / (PL[0]+PL[1]) per (b,h,qt) tile ----
__global__ __launch_bounds__(256) void combine_split(
    const float* __restrict__ PO, const float* __restrict__ PL,
    float* __restrict__ O)
{
    const int tq = blockIdx.x;            // 512 = b*256 + h*16 + qt
    const int b = tq >> 8, h = (tq >> 4) & 15, qt = tq & 15;
    const float* p0 = PO + (size_t)tq * 2 * (BQ * DH);
    const float* p1 = p0 + BQ * DH;
    const float* l0 = PL + (size_t)tq * 2 * BQ;
    const float* l1 = l0 + BQ;
    const int t = threadIdx.x;
    #pragma unroll
    for (int k = 0; k < 8; ++k) {
        const int e   = (t + k * 256) * 4;     // elem index (4-aligned)
        const int row = e >> 6, col = e & 63;
        f32x4 a = *(const f32x4*)(p0 + e);
        f32x4 c = *(const f32x4*)(p1 + e);
        const float rl = 1.f / (l0[row] + l1[row]);
        f32x4 r;
        #pragma unroll
        for (int j = 0; j < 4; ++j) r[j] = (a[j] + c[j]) * rl;
        *(f32x4*)(O + (size_t)(b * S_LEN + qt * BQ + row) * D_MODEL + h * DH + col) = r;
    }
}

extern "C" void kernel_launch(void* const* d_in, const int* in_sizes, int n_in,
                              void* d_out, int out_size, void* d_ws, size_t ws_size,
                              hipStream_t stream) {
    const float* Q = (const float*)d_in[0];
    const float* K = (const float*)d_in[1];
    const float* V = (const float*)d_in[2];
    const int*   M = (const int*)d_in[3];
    float*       O = (float*)d_out;

    const size_t NEL = (size_t)2 * S_LEN * D_MODEL;            // 4,194,304
    const size_t VT_BYTES = NEL * sizeof(unsigned short);      // 8 MB
    const size_t KB_BYTES = NEL * sizeof(unsigned short);      // 8 MB
    const size_t MB_BYTES = (size_t)2 * S_LEN * 32 * 8;        // 1 MB
    const size_t PO_BYTES = (size_t)512 * 2 * BQ * DH * 4;     // 32 MB
    const size_t PL_BYTES = (size_t)512 * 2 * BQ * 4;          // 0.5 MB

    if (ws_size >= VT_BYTES + KB_BYTES + MB_BYTES + PO_BYTES + PL_BYTES) {
        // 49.5 MB: split-K path (2x TLP) + combine
        unsigned short* VT = (unsigned short*)d_ws;
        unsigned short* KB = (unsigned short*)((char*)d_ws + VT_BYTES);
        unsigned long long* Mb = (unsigned long long*)((char*)d_ws + VT_BYTES + KB_BYTES);
        float* PO = (float*)((char*)d_ws + VT_BYTES + KB_BYTES + MB_BYTES);
        float* PL = (float*)((char*)d_ws + VT_BYTES + KB_BYTES + MB_BYTES + PO_BYTES);
        hipLaunchKernelGGL(cvt_fused, dim3(3072), dim3(256), 0, stream, V, M, K, VT, Mb, KB);
        hipLaunchKernelGGL(mha_fwd_v18, dim3(1024), dim3(256), 0, stream,
                           Q, K, KB, VT, Mb, O, PO, PL, 1, 1);
        hipLaunchKernelGGL(combine_split, dim3(512), dim3(256), 0, stream, PO, PL, O);
    } else if (ws_size >= VT_BYTES + KB_BYTES + MB_BYTES) {    // 17 MB: unsplit (v15)
        unsigned short* VT = (unsigned short*)d_ws;
        unsigned short* KB = (unsigned short*)((char*)d_ws + VT_BYTES);
        unsigned long long* Mb = (unsigned long long*)((char*)d_ws + VT_BYTES + KB_BYTES);
        hipLaunchKernelGGL(cvt_fused, dim3(3072), dim3(256), 0, stream, V, M, K, VT, Mb, KB);
        hipLaunchKernelGGL(mha_fwd_v18, dim3(512), dim3(256), 0, stream,
                           Q, K, KB, VT, Mb, O, (float*)0, (float*)0, 1, 0);
    } else {                                                   // 9 MB: inline K convert
        unsigned short* VT = (unsigned short*)d_ws;
        unsigned long long* Mb = (unsigned long long*)((char*)d_ws + VT_BYTES);
        hipLaunchKernelGGL(cvt_fused, dim3(2048), dim3(256), 0, stream, V, M, K, VT, Mb, (unsigned short*)0);
        hipLaunchKernelGGL(mha_fwd_v18, dim3(512), dim3(256), 0, stream,
                           Q, K, (const unsigned short*)0, VT, Mb, O, (float*)0, (float*)0, 0, 0);
    }
}

// Round 16
// 180.663 us; speedup vs baseline: 1.0041x; 1.0041x over previous
//
#include <hip/hip_runtime.h>

#define S_LEN 2048
#define D_MODEL 1024
#define DH 64      // head dim
#define BK 128     // keys per k-tile
#define ZSCALE 0.18033688f   // 0.125 * log2(e) — folded into Q fragments

using short8 = __attribute__((ext_vector_type(8))) short;
using s4v    = __attribute__((ext_vector_type(4))) short;
using f32x4  = __attribute__((ext_vector_type(4))) float;
using u32x4  = __attribute__((ext_vector_type(4))) unsigned int;

#define BMM(a, b, c) __builtin_amdgcn_mfma_f32_16x16x32_bf16((a), (b), (c), 0, 0, 0)

__device__ __forceinline__ unsigned short f2bf(float x) {
    union { float f; unsigned int u; } c; c.f = x;
    unsigned int u = c.u;
    u += 0x7fffu + ((u >> 16) & 1u);   // RNE
    return (unsigned short)(u >> 16);
}

// ---- fused converter (verified) ----
__global__ __launch_bounds__(256) void cvt_fused(const float* __restrict__ V,
                                                 const int* __restrict__ M,
                                                 const float* __restrict__ K,
                                                 unsigned short* __restrict__ VT,
                                                 unsigned long long* __restrict__ Mb,
                                                 unsigned short* __restrict__ KB) {
    const int blk = blockIdx.x;
    const int tid = threadIdx.x;
    if (blk < 1024) {
        __shared__ float tsF[64][65];
        const int b  = blk >> 9;
        const int h  = (blk >> 5) & 15;
        const int s0 = (blk & 31) * 64;
        #pragma unroll
        for (int it = 0; it < 2; ++it) {
            int seg = tid + it * 256;
            int s = seg >> 3, d8 = (seg & 7) << 3;
            const float* p = V + (size_t)(b * S_LEN + s0 + s) * D_MODEL + h * DH + d8;
            f32x4 a = *(const f32x4*)p;
            f32x4 c = *(const f32x4*)(p + 4);
            #pragma unroll
            for (int j = 0; j < 4; ++j) { tsF[s][d8 + j] = a[j]; tsF[s][d8 + 4 + j] = c[j]; }
        }
        __syncthreads();
        #pragma unroll
        for (int it = 0; it < 2; ++it) {
            int seg = tid + it * 256;
            int d = seg >> 3, s8 = (seg & 7) << 3;
            short8 w;
            #pragma unroll
            for (int j = 0; j < 8; ++j) w[j] = (short)f2bf(tsF[s8 + j][d]);
            *(short8*)(VT + ((size_t)((b * 16 + h) * 64 + d)) * S_LEN + s0 + s8) = w;
        }
    } else if (blk < 2048) {
        const int pb   = blk - 1024;
        const int wave = tid >> 6, lane = tid & 63;
        const int row  = pb * 4 + wave;
        const int* mp  = M + (size_t)row * S_LEN;
        #pragma unroll 4
        for (int it = 0; it < 32; ++it) {
            int m = mp[it * 64 + lane];
            unsigned long long bal = __ballot(m != 0);
            if (lane == 0) Mb[(size_t)row * 32 + it] = bal;
        }
    } else {
        size_t base = (size_t)(blk - 2048) * 4096;
        #pragma unroll
        for (int it = 0; it < 4; ++it) {
            size_t i = base + ((size_t)(it * 256 + tid)) * 4;
            f32x4 a = *(const f32x4*)(K + i);
            s4v w;
            #pragma unroll
            for (int j = 0; j < 4; ++j) w[j] = (short)f2bf(a[j]);
            *(s4v*)(KB + i) = w;
        }
    }
}

// ---- v19: v15's verified per-wave body re-tiled to 512-THREAD blocks
//      (8 waves x 32 q-rows = BQ 256) + split-K halves -> grid 512.
//      Under the measured 2-workgroup/CU cap this gives 16 waves/CU
//      (4/SIMD), doubling latency-hiding TLP.  Writes exact partials.
__global__ __launch_bounds__(512) void mha_fwd_v19(
    const float* __restrict__ Q,
    const unsigned short* __restrict__ KB,   // bf16 preconverted
    const unsigned short* __restrict__ VT,   // bf16 pre-transposed [d][s]
    const unsigned long long* __restrict__ Mb, // packed mask u64, 32/row
    float* __restrict__ PO,                  // partial Sum p*V  [pblk][256][64]
    float* __restrict__ PL)                  // partial Sum p    [pblk][256]
{
    __shared__ alignas(16) unsigned short Ks[BK][64];   // 16 KB
    __shared__ alignas(16) unsigned short Vt[DH][128];  // 16 KB

    // XCD-chunked swizzle: nwg=512 -> each XCD gets 64 contiguous blk
    const int blk0 = blockIdx.x;
    const int blk  = ((blk0 & 7) << 6) | (blk0 >> 3);

    const int b     = blk >> 8;
    const int h     = (blk >> 4) & 15;
    const int qt    = (blk >> 1) & 7;
    const int split = blk & 1;
    const int qbase = qt * 256;
    const int bh    = b * 16 + h;
    const int kb0   = split * (S_LEN / 2);
    const int kbend = kb0 + S_LEN / 2;

    const int tid  = threadIdx.x;
    const int wave = tid >> 6;           // 0..7
    const int lane = tid & 63;
    const int n16  = lane & 15;
    const int quad = lane >> 4;
    const int bq   = quad << 3;          // mask half-word shift
    const int n7   = n16 & 7;

    // K staging: 512 thr cover 64 rows x 64 cols per round (2 rounds), sigma rows
    const int srow = tid >> 3;           // 0..63
    const int prow = ((srow >> 5) << 5) | (((srow >> 2) & 1) << 4)
                   | (((srow >> 3) & 3) << 2) | (srow & 3);
    // V staging: 512 thr cover 32 rows x 128 cols per round (2 rounds)
    const int vrow = tid >> 4;           // 0..31

    // LDS XOR-swizzle columns (16B granules; phys = logical ^ (row & (ng-1)))
    const int kwcol = (((tid & 7) ^ (prow & 7)) << 3);
    const int vwcol = (((tid & 15) ^ (vrow & 15)) << 3);
    const int krc0  = ((quad ^ n7) << 3);
    const int krc1  = krc0 ^ 32;
    int vrc[4];
    #pragma unroll
    for (int kc = 0; kc < 4; ++kc) vrc[kc] = (((kc * 4 + quad) ^ n16) << 3);

    // Q fragments (B operand), PRE-SCALED by ZSCALE; wave owns rows wave*32+qg*16+n16
    short8 qf[2][2];
    #pragma unroll
    for (int qg = 0; qg < 2; ++qg) {
        const size_t qoff = (size_t)(b * S_LEN + qbase + wave * 32 + qg * 16 + n16) * D_MODEL
                          + h * DH + quad * 8;
        f32x4 a0 = *(const f32x4*)(Q + qoff);
        f32x4 a1 = *(const f32x4*)(Q + qoff + 4);
        f32x4 a2 = *(const f32x4*)(Q + qoff + 32);
        f32x4 a3 = *(const f32x4*)(Q + qoff + 36);
        short8 q0, q1;
        #pragma unroll
        for (int j = 0; j < 4; ++j) {
            q0[j] = (short)f2bf(a0[j] * ZSCALE); q0[4 + j] = (short)f2bf(a1[j] * ZSCALE);
            q1[j] = (short)f2bf(a2[j] * ZSCALE); q1[4 + j] = (short)f2bf(a3[j] * ZSCALE);
        }
        qf[qg][0] = q0; qf[qg][1] = q1;
    }

    const short8 ones = {0x3F80,0x3F80,0x3F80,0x3F80,0x3F80,0x3F80,0x3F80,0x3F80}; // bf16 1.0

    f32x4 o[2][4], o4[2];
    #pragma unroll
    for (int qg = 0; qg < 2; ++qg) {
        #pragma unroll
        for (int dg = 0; dg < 4; ++dg) o[qg][dg] = f32x4{0.f,0.f,0.f,0.f};
        o4[qg] = f32x4{0.f,0.f,0.f,0.f};
    }

    const unsigned long long* mrow[2];
    #pragma unroll
    for (int qg = 0; qg < 2; ++qg)
        mrow[qg] = Mb + (size_t)(b * S_LEN + qbase + wave * 32 + qg * 16 + n16) * 32;

    const size_t kbase = (size_t)(b * S_LEN) * D_MODEL + h * DH;
    const size_t vbase = (size_t)(bh * 64) * S_LEN;

    // ---- prologue: prefetch tile kb0 into regs (2 rounds each for K,V) ----
    short8 ka[2], va[2];
    unsigned long long mw[2][2];
    #pragma unroll
    for (int i = 0; i < 2; ++i)
        ka[i] = *(const short8*)(KB + kbase + (size_t)(kb0 + i * 64 + srow) * D_MODEL + ((tid & 7) << 3));
    #pragma unroll
    for (int i = 0; i < 2; ++i)   // VT is [d][s]: tile offset on the COLUMN
        va[i] = *(const short8*)(VT + vbase + (size_t)(vrow + 32 * i) * S_LEN + kb0 + ((tid & 15) << 3));
    {
        const int wi = kb0 >> 6;
        #pragma unroll
        for (int qg = 0; qg < 2; ++qg) { mw[qg][0] = mrow[qg][wi]; mw[qg][1] = mrow[qg][wi + 1]; }
    }

    for (int kb = kb0; kb < kbend; kb += BK) {
        // barrier 1: all waves done READING prev tile; raw (no vmcnt drain)
        __builtin_amdgcn_s_barrier();
        __builtin_amdgcn_sched_barrier(0);

        // stage tile (swizzled columns; sigma-permuted K rows)
        #pragma unroll
        for (int i = 0; i < 2; ++i) {
            *(short8*)&Ks[prow + 64 * i][kwcol] = ka[i];
            *(short8*)&Vt[vrow + 32 * i][vwcol] = va[i];
        }

        // issue next tile's loads — consumed by NEXT iteration's ds_writes
        const int kn = kb + BK;
        const bool more = kn < kbend;
        short8 nka[2], nva[2];
        unsigned long long nmw[2][2];
        if (more) {
            #pragma unroll
            for (int i = 0; i < 2; ++i)
                nka[i] = *(const short8*)(KB + kbase + (size_t)(kn + i * 64 + srow) * D_MODEL + ((tid & 7) << 3));
            #pragma unroll
            for (int i = 0; i < 2; ++i)
                nva[i] = *(const short8*)(VT + vbase + (size_t)(vrow + 32 * i) * S_LEN + kn + ((tid & 15) << 3));
            const int wi = kn >> 6;
            #pragma unroll
            for (int qg = 0; qg < 2; ++qg) { nmw[qg][0] = mrow[qg][wi]; nmw[qg][1] = mrow[qg][wi + 1]; }
        }

        // mask half-words (register-only; off the post-barrier path)
        unsigned int am[2][4];
        #pragma unroll
        for (int qg = 0; qg < 2; ++qg) {
            am[qg][0] = ((unsigned int)mw[qg][0]) >> bq;
            am[qg][1] = ((unsigned int)(mw[qg][0] >> 32)) >> bq;
            am[qg][2] = ((unsigned int)mw[qg][1]) >> bq;
            am[qg][3] = ((unsigned int)(mw[qg][1] >> 32)) >> bq;
        }

        // barrier 2: my LDS writes committed (lgkm only), then all waves sync
        asm volatile("s_waitcnt lgkmcnt(0)" ::: "memory");
        __builtin_amdgcn_s_barrier();
        __builtin_amdgcn_sched_barrier(0);

        // ---- interleaved compute: PV[kc] fires right after its two QK cts ----
        u32x4 Af[2][4];   // [qg][kc]
        auto QKCT = [&](int ct) {
            short8 kf0 = *(const short8*)&Ks[ct * 16 + n16][krc0];
            short8 kf1 = *(const short8*)&Ks[ct * 16 + n16][krc1];
            f32x4 sA = {0.f,0.f,0.f,0.f}, sB = sA;
            sA = BMM(kf0, qf[0][0], sA); sA = BMM(kf1, qf[0][1], sA);
            sB = BMM(kf0, qf[1][0], sB); sB = BMM(kf1, qf[1][1], sB);
            unsigned int puA[4], puB[4];
            #pragma unroll
            for (int r = 0; r < 4; ++r) {
                puA[r] = __float_as_uint(__builtin_amdgcn_exp2f(sA[r]));
                puB[r] = __float_as_uint(__builtin_amdgcn_exp2f(sB[r]));
            }
            const int sel = ct >> 1, sb = (ct & 1) * 4, kc = ct >> 1, ub = (ct & 1) * 2;
            unsigned int nibA = (am[0][sel] >> sb) & 0xFu;
            unsigned int nibB = (am[1][sel] >> sb) & 0xFu;
            unsigned int m8A = ((nibA * 0x00204081u) & 0x01010101u) * 0xFFu;
            unsigned int m8B = ((nibB * 0x00204081u) & 0x01010101u) * 0xFFu;
            Af[0][kc][ub + 0] = __builtin_amdgcn_perm(puA[1], puA[0], 0x07060302u)
                              & __builtin_amdgcn_perm(0u, m8A, 0x01010000u);
            Af[0][kc][ub + 1] = __builtin_amdgcn_perm(puA[3], puA[2], 0x07060302u)
                              & __builtin_amdgcn_perm(0u, m8A, 0x03030202u);
            Af[1][kc][ub + 0] = __builtin_amdgcn_perm(puB[1], puB[0], 0x07060302u)
                              & __builtin_amdgcn_perm(0u, m8B, 0x01010000u);
            Af[1][kc][ub + 1] = __builtin_amdgcn_perm(puB[3], puB[2], 0x07060302u)
                              & __builtin_amdgcn_perm(0u, m8B, 0x03030202u);
        };
        auto PVKC = [&](int kc) {
            short8 v0 = *(const short8*)&Vt[      n16][vrc[kc]];
            short8 v1 = *(const short8*)&Vt[16 + n16][vrc[kc]];
            short8 v2 = *(const short8*)&Vt[32 + n16][vrc[kc]];
            short8 v3 = *(const short8*)&Vt[48 + n16][vrc[kc]];
            union { u32x4 u; short8 s; } c0, c1;
            c0.u = Af[0][kc]; c1.u = Af[1][kc];
            o[0][0] = BMM(c0.s, v0, o[0][0]); o[0][1] = BMM(c0.s, v1, o[0][1]);
            o[0][2] = BMM(c0.s, v2, o[0][2]); o[0][3] = BMM(c0.s, v3, o[0][3]);
            o4[0]   = BMM(c0.s, ones, o4[0]);
            o[1][0] = BMM(c1.s, v0, o[1][0]); o[1][1] = BMM(c1.s, v1, o[1][1]);
            o[1][2] = BMM(c1.s, v2, o[1][2]); o[1][3] = BMM(c1.s, v3, o[1][3]);
            o4[1]   = BMM(c1.s, ones, o4[1]);
        };

        __builtin_amdgcn_s_setprio(1);
        QKCT(0); QKCT(1);
        PVKC(0);
        QKCT(2); QKCT(3);
        PVKC(1);
        QKCT(4); QKCT(5);
        PVKC(2);
        QKCT(6); QKCT(7);
        PVKC(3);
        __builtin_amdgcn_s_setprio(0);

        if (more) {
            #pragma unroll
            for (int i = 0; i < 2; ++i) { ka[i] = nka[i]; va[i] = nva[i]; }
            #pragma unroll
            for (int qg = 0; qg < 2; ++qg) { mw[qg][0] = nmw[qg][0]; mw[qg][1] = nmw[qg][1]; }
        }
    }

    // split epilogue: raw partials (exact combine later)
    {
        const int pblk = ((bh * 8 + qt) << 1) + split;
        float* pp = PO + (size_t)pblk * (256 * DH);
        float* pl = PL + (size_t)pblk * 256;
        #pragma unroll
        for (int qg = 0; qg < 2; ++qg) {
            #pragma unroll
            for (int r = 0; r < 4; ++r) {
                const int rowin = wave * 32 + qg * 16 + quad * 4 + r;
                float* op = pp + rowin * DH + n16;
                op[0]  = o[qg][0][r];
                op[16] = o[qg][1][r];
                op[32] = o[qg][2][r];
                op[48] = o[qg][3][r];
                if (n16 == 0) pl[rowin] = o4[qg][r];
            }
        }
    }
}

// ---- combine: O = (PO[0]+PO[1]) / (PL[0]+PL[1]) per (b,h,qt) 256-row tile ----
__global__ __launch_bounds__(256) void combine_split2(
    const float* __restrict__ PO, const float* __restrict__ PL,
    float* __restrict__ O)
{
    const int tq = blockIdx.x;            // 256 = b*128 + h*8 + qt
    const int b = tq >> 7, h = (tq >> 3) & 15, qt = tq & 7;
    const float* p0 = PO + (size_t)tq * 2 * (256 * DH);
    const float* p1 = p0 + 256 * DH;
    const float* l0 = PL + (size_t)tq * 2 * 256;
    const float* l1 = l0 + 256;
    const int t = threadIdx.x;
    #pragma unroll
    for (int k = 0; k < 16; ++k) {
        const int e   = (t + k * 256) * 4;     // elem index (4-aligned)
        const int row = e >> 6, col = e & 63;
        f32x4 a = *(const f32x4*)(p0 + e);
        f32x4 c = *(const f32x4*)(p1 + e);
        const float rl = 1.f / (l0[row] + l1[row]);
        f32x4 r;
        #pragma unroll
        for (int j = 0; j < 4; ++j) r[j] = (a[j] + c[j]) * rl;
        *(f32x4*)(O + (size_t)(b * S_LEN + qt * 256 + row) * D_MODEL + h * DH + col) = r;
    }
}

// ---- fallback: v15 (verified, 256-thr, unsplit, direct O write) ----
__global__ __launch_bounds__(256) void mha_fwd_v15f(
    const float* __restrict__ Q,
    const float* __restrict__ K,
    const unsigned short* __restrict__ KB,
    const unsigned short* __restrict__ VT,
    const unsigned long long* __restrict__ Mb,
    float* __restrict__ O,
    int kbf)
{
    __shared__ alignas(16) unsigned short Ks[BK][64];
    __shared__ alignas(16) unsigned short Vt[DH][128];

    const int blk0 = blockIdx.x;
    const int blk  = ((blk0 & 7) << 6) | (blk0 >> 3);
    const int b   = blk >> 8;
    const int h   = (blk >> 4) & 15;
    const int qbase = (blk & 15) * 128;
    const int bh  = b * 16 + h;

    const int tid  = threadIdx.x;
    const int wave = tid >> 6;
    const int lane = tid & 63;
    const int n16  = lane & 15;
    const int quad = lane >> 4;
    const int bq   = quad << 3;
    const int n7   = n16 & 7;

    const int srow = tid >> 3;
    const int prow = (((srow >> 2) & 1) << 4) | (((srow >> 3) & 3) << 2) | (srow & 3);
    const int vrow = tid >> 4;
    const int kwcol = (((tid & 7) ^ (prow & 7)) << 3);
    const int vwcol = (((tid & 15) ^ vrow) << 3);
    const int krc0  = ((quad ^ n7) << 3);
    const int krc1  = krc0 ^ 32;
    int vrc[4];
    #pragma unroll
    for (int kc = 0; kc < 4; ++kc) vrc[kc] = (((kc * 4 + quad) ^ n16) << 3);

    short8 qf[2][2];
    #pragma unroll
    for (int qg = 0; qg < 2; ++qg) {
        const size_t qoff = (size_t)(b * S_LEN + qbase + wave * 32 + qg * 16 + n16) * D_MODEL
                          + h * DH + quad * 8;
        f32x4 a0 = *(const f32x4*)(Q + qoff);
        f32x4 a1 = *(const f32x4*)(Q + qoff + 4);
        f32x4 a2 = *(const f32x4*)(Q + qoff + 32);
        f32x4 a3 = *(const f32x4*)(Q + qoff + 36);
        short8 q0, q1;
        #pragma unroll
        for (int j = 0; j < 4; ++j) {
            q0[j] = (short)f2bf(a0[j] * ZSCALE); q0[4 + j] = (short)f2bf(a1[j] * ZSCALE);
            q1[j] = (short)f2bf(a2[j] * ZSCALE); q1[4 + j] = (short)f2bf(a3[j] * ZSCALE);
        }
        qf[qg][0] = q0; qf[qg][1] = q1;
    }

    const short8 ones = {0x3F80,0x3F80,0x3F80,0x3F80,0x3F80,0x3F80,0x3F80,0x3F80};

    f32x4 o[2][4], o4[2];
    #pragma unroll
    for (int qg = 0; qg < 2; ++qg) {
        #pragma unroll
        for (int dg = 0; dg < 4; ++dg) o[qg][dg] = f32x4{0.f,0.f,0.f,0.f};
        o4[qg] = f32x4{0.f,0.f,0.f,0.f};
    }

    const unsigned long long* mrow[2];
    #pragma unroll
    for (int qg = 0; qg < 2; ++qg)
        mrow[qg] = Mb + (size_t)(b * S_LEN + qbase + wave * 32 + qg * 16 + n16) * 32;

    const size_t kbase = (size_t)(b * S_LEN) * D_MODEL + h * DH;
    const size_t vbase = (size_t)(bh * 64) * S_LEN;

    short8 ka[4], va[4];
    unsigned long long mw[2][2];
    if (kbf) {
        #pragma unroll
        for (int i = 0; i < 4; ++i)
            ka[i] = *(const short8*)(KB + kbase + (size_t)(i * 32 + srow) * D_MODEL + ((tid & 7) << 3));
    } else {
        #pragma unroll
        for (int i = 0; i < 4; ++i) {
            const float* kp = K + kbase + (size_t)(i * 32 + srow) * D_MODEL + ((tid & 7) << 3);
            f32x4 p0 = *(const f32x4*)kp, p1 = *(const f32x4*)(kp + 4);
            short8 w;
            #pragma unroll
            for (int j = 0; j < 4; ++j) { w[j] = (short)f2bf(p0[j]); w[4 + j] = (short)f2bf(p1[j]); }
            ka[i] = w;
        }
    }
    #pragma unroll
    for (int i = 0; i < 4; ++i)
        va[i] = *(const short8*)(VT + vbase + (size_t)(vrow + 16 * i) * S_LEN + ((tid & 15) << 3));
    #pragma unroll
    for (int qg = 0; qg < 2; ++qg) { mw[qg][0] = mrow[qg][0]; mw[qg][1] = mrow[qg][1]; }

    for (int kb = 0; kb < S_LEN; kb += BK) {
        __builtin_amdgcn_s_barrier();
        __builtin_amdgcn_sched_barrier(0);
        #pragma unroll
        for (int i = 0; i < 4; ++i) {
            *(short8*)&Ks[prow + 32 * i][kwcol] = ka[i];
            *(short8*)&Vt[vrow + 16 * i][vwcol] = va[i];
        }
        const int kn = kb + BK;
        const bool more = kn < S_LEN;
        short8 nka[4], nva[4];
        unsigned long long nmw[2][2];
        if (more) {
            if (kbf) {
                #pragma unroll
                for (int i = 0; i < 4; ++i)
                    nka[i] = *(const short8*)(KB + kbase + (size_t)(kn + i * 32 + srow) * D_MODEL + ((tid & 7) << 3));
            } else {
                #pragma unroll
                for (int i = 0; i < 4; ++i) {
                    const float* kp = K + kbase + (size_t)(kn + i * 32 + srow) * D_MODEL + ((tid & 7) << 3);
                    f32x4 p0 = *(const f32x4*)kp, p1 = *(const f32x4*)(kp + 4);
                    short8 w;
                    #pragma unroll
                    for (int j = 0; j < 4; ++j) { w[j] = (short)f2bf(p0[j]); w[4 + j] = (short)f2bf(p1[j]); }
                    nka[i] = w;
                }
            }
            #pragma unroll
            for (int i = 0; i < 4; ++i)
                nva[i] = *(const short8*)(VT + vbase + (size_t)(vrow + 16 * i) * S_LEN + kn + ((tid & 15) << 3));
            const int wi = kn >> 6;
            #pragma unroll
            for (int qg = 0; qg < 2; ++qg) { nmw[qg][0] = mrow[qg][wi]; nmw[qg][1] = mrow[qg][wi + 1]; }
        }
        unsigned int am[2][4];
        #pragma unroll
        for (int qg = 0; qg < 2; ++qg) {
            am[qg][0] = ((unsigned int)mw[qg][0]) >> bq;
            am[qg][1] = ((unsigned int)(mw[qg][0] >> 32)) >> bq;
            am[qg][2] = ((unsigned int)mw[qg][1]) >> bq;
            am[qg][3] = ((unsigned int)(mw[qg][1] >> 32)) >> bq;
        }
        asm volatile("s_waitcnt lgkmcnt(0)" ::: "memory");
        __builtin_amdgcn_s_barrier();
        __builtin_amdgcn_sched_barrier(0);

        u32x4 Af[2][4];
        auto QKCT = [&](int ct) {
            short8 kf0 = *(const short8*)&Ks[ct * 16 + n16][krc0];
            short8 kf1 = *(const short8*)&Ks[ct * 16 + n16][krc1];
            f32x4 sA = {0.f,0.f,0.f,0.f}, sB = sA;
            sA = BMM(kf0, qf[0][0], sA); sA = BMM(kf1, qf[0][1], sA);
            sB = BMM(kf0, qf[1][0], sB); sB = BMM(kf1, qf[1][1], sB);
            unsigned int puA[4], puB[4];
            #pragma unroll
            for (int r = 0; r < 4; ++r) {
                puA[r] = __float_as_uint(__builtin_amdgcn_exp2f(sA[r]));
                puB[r] = __float_as_uint(__builtin_amdgcn_exp2f(sB[r]));
            }
            const int sel = ct >> 1, sb = (ct & 1) * 4, kc = ct >> 1, ub = (ct & 1) * 2;
            unsigned int nibA = (am[0][sel] >> sb) & 0xFu;
            unsigned int nibB = (am[1][sel] >> sb) & 0xFu;
            unsigned int m8A = ((nibA * 0x00204081u) & 0x01010101u) * 0xFFu;
            unsigned int m8B = ((nibB * 0x00204081u) & 0x01010101u) * 0xFFu;
            Af[0][kc][ub + 0] = __builtin_amdgcn_perm(puA[1], puA[0], 0x07060302u)
                              & __builtin_amdgcn_perm(0u, m8A, 0x01010000u);
            Af[0][kc][ub + 1] = __builtin_amdgcn_perm(puA[3], puA[2], 0x07060302u)
                              & __builtin_amdgcn_perm(0u, m8A, 0x03030202u);
            Af[1][kc][ub + 0] = __builtin_amdgcn_perm(puB[1], puB[0], 0x07060302u)
                              & __builtin_amdgcn_perm(0u, m8B, 0x01010000u);
            Af[1][kc][ub + 1] = __builtin_amdgcn_perm(puB[3], puB[2], 0x07060302u)
                              & __builtin_amdgcn_perm(0u, m8B, 0x03030202u);
        };
        auto PVKC = [&](int kc) {
            short8 v0 = *(const short8*)&Vt[      n16][vrc[kc]];
            short8 v1 = *(const short8*)&Vt[16 + n16][vrc[kc]];
            short8 v2 = *(const short8*)&Vt[32 + n16][vrc[kc]];
            short8 v3 = *(const short8*)&Vt[48 + n16][vrc[kc]];
            union { u32x4 u; short8 s; } c0, c1;
            c0.u = Af[0][kc]; c1.u = Af[1][kc];
            o[0][0] = BMM(c0.s, v0, o[0][0]); o[0][1] = BMM(c0.s, v1, o[0][1]);
            o[0][2] = BMM(c0.s, v2, o[0][2]); o[0][3] = BMM(c0.s, v3, o[0][3]);
            o4[0]   = BMM(c0.s, ones, o4[0]);
            o[1][0] = BMM(c1.s, v0, o[1][0]); o[1][1] = BMM(c1.s, v1, o[1][1]);
            o[1][2] = BMM(c1.s, v2, o[1][2]); o[1][3] = BMM(c1.s, v3, o[1][3]);
            o4[1]   = BMM(c1.s, ones, o4[1]);
        };

        __builtin_amdgcn_s_setprio(1);
        QKCT(0); QKCT(1);
        PVKC(0);
        QKCT(2); QKCT(3);
        PVKC(1);
        QKCT(4); QKCT(5);
        PVKC(2);
        QKCT(6); QKCT(7);
        PVKC(3);
        __builtin_amdgcn_s_setprio(0);

        if (more) {
            #pragma unroll
            for (int i = 0; i < 4; ++i) { ka[i] = nka[i]; va[i] = nva[i]; }
            #pragma unroll
            for (int qg = 0; qg < 2; ++qg) { mw[qg][0] = nmw[qg][0]; mw[qg][1] = nmw[qg][1]; }
        }
    }

    #pragma unroll
    for (int qg = 0; qg < 2; ++qg) {
        #pragma unroll
        for (int r = 0; r < 4; ++r) {
            float rl = 1.f / o4[qg][r];
            size_t row = (size_t)(b * S_LEN + qbase + wave * 32 + qg * 16 + quad * 4 + r);
            float* op = O + row * D_MODEL + h * DH + n16;
            op[0]  = o[qg][0][r] * rl;
            op[16] = o[qg][1][r] * rl;
            op[32] = o[qg][2][r] * rl;
            op[48] = o[qg][3][r] * rl;
        }
    }
}

extern "C" void kernel_launch(void* const* d_in, const int* in_sizes, int n_in,
                              void* d_out, int out_size, void* d_ws, size_t ws_size,
                              hipStream_t stream) {
    const float* Q = (const float*)d_in[0];
    const float* K = (const float*)d_in[1];
    const float* V = (const float*)d_in[2];
    const int*   M = (const int*)d_in[3];
    float*       O = (float*)d_out;

    const size_t NEL = (size_t)2 * S_LEN * D_MODEL;            // 4,194,304
    const size_t VT_BYTES = NEL * sizeof(unsigned short);      // 8 MB
    const size_t KB_BYTES = NEL * sizeof(unsigned short);      // 8 MB
    const size_t MB_BYTES = (size_t)2 * S_LEN * 32 * 8;        // 1 MB
    const size_t PO_BYTES = (size_t)512 * 256 * DH * 4;        // 32 MB
    const size_t PL_BYTES = (size_t)512 * 256 * 4;             // 0.5 MB

    if (ws_size >= VT_BYTES + KB_BYTES + MB_BYTES + PO_BYTES + PL_BYTES) {
        // 49.5 MB: 512-thread split-K path (16 waves/CU target) + combine
        unsigned short* VT = (unsigned short*)d_ws;
        unsigned short* KB = (unsigned short*)((char*)d_ws + VT_BYTES);
        unsigned long long* Mb = (unsigned long long*)((char*)d_ws + VT_BYTES + KB_BYTES);
        float* PO = (float*)((char*)d_ws + VT_BYTES + KB_BYTES + MB_BYTES);
        float* PL = (float*)((char*)d_ws + VT_BYTES + KB_BYTES + MB_BYTES + PO_BYTES);
        hipLaunchKernelGGL(cvt_fused, dim3(3072), dim3(256), 0, stream, V, M, K, VT, Mb, KB);
        hipLaunchKernelGGL(mha_fwd_v19, dim3(512), dim3(512), 0, stream,
                           Q, KB, VT, Mb, PO, PL);
        hipLaunchKernelGGL(combine_split2, dim3(256), dim3(256), 0, stream, PO, PL, O);
    } else if (ws_size >= VT_BYTES + KB_BYTES + MB_BYTES) {    // 17 MB: unsplit (v15)
        unsigned short* VT = (unsigned short*)d_ws;
        unsigned short* KB = (unsigned short*)((char*)d_ws + VT_BYTES);
        unsigned long long* Mb = (unsigned long long*)((char*)d_ws + VT_BYTES + KB_BYTES);
        hipLaunchKernelGGL(cvt_fused, dim3(3072), dim3(256), 0, stream, V, M, K, VT, Mb, KB);
        hipLaunchKernelGGL(mha_fwd_v15f, dim3(512), dim3(256), 0, stream,
                           Q, K, KB, VT, Mb, O, 1);
    } else {                                                   // 9 MB: inline K convert
        unsigned short* VT = (unsigned short*)d_ws;
        unsigned long long* Mb = (unsigned long long*)((char*)d_ws + VT_BYTES);
        hipLaunchKernelGGL(cvt_fused, dim3(2048), dim3(256), 0, stream, V, M, K, VT, Mb, (unsigned short*)0);
        hipLaunchKernelGGL(mha_fwd_v15f, dim3(512), dim3(256), 0, stream,
                           Q, K, (unsigned short*)0, VT, Mb, O, 0);
    }
}

// Round 17
// 171.714 us; speedup vs baseline: 1.0565x; 1.0521x over previous
//
#include <hip/hip_runtime.h>

#define S_LEN 2048
#define D_MODEL 1024
#define DH 64      // head dim
#define BQ 128     // q rows per block (32 per wave)
#define BK 128     // keys per k-tile
#define ZSCALE 0.18033688f   // 0.125 * log2(e) — folded into Q fragments

using short8 = __attribute__((ext_vector_type(8))) short;
using s4v    = __attribute__((ext_vector_type(4))) short;
using f32x4  = __attribute__((ext_vector_type(4))) float;
using u32x4  = __attribute__((ext_vector_type(4))) unsigned int;

#define BMM(a, b, c) __builtin_amdgcn_mfma_f32_16x16x32_bf16((a), (b), (c), 0, 0, 0)

__device__ __forceinline__ unsigned short f2bf(float x) {
    union { float f; unsigned int u; } c; c.f = x;
    unsigned int u = c.u;
    u += 0x7fffu + ((u >> 16) & 1u);   // RNE
    return (unsigned short)(u >> 16);
}

// ---- fused converter (verified) ----
// blocks [0,1024): V f32 -> bf16 transposed VT[(b*16+h)*64+d][s]
// blocks [1024,2048): mask int32 -> packed bits Mb[row][32] (u64 per 64 cols)
// blocks [2048,3072): K f32 -> bf16 KB   [only when grid=3072]
__global__ __launch_bounds__(256) void cvt_fused(const float* __restrict__ V,
                                                 const int* __restrict__ M,
                                                 const float* __restrict__ K,
                                                 unsigned short* __restrict__ VT,
                                                 unsigned long long* __restrict__ Mb,
                                                 unsigned short* __restrict__ KB) {
    const int blk = blockIdx.x;
    const int tid = threadIdx.x;
    if (blk < 1024) {
        __shared__ float tsF[64][65];
        const int b  = blk >> 9;
        const int h  = (blk >> 5) & 15;
        const int s0 = (blk & 31) * 64;
        #pragma unroll
        for (int it = 0; it < 2; ++it) {
            int seg = tid + it * 256;
            int s = seg >> 3, d8 = (seg & 7) << 3;
            const float* p = V + (size_t)(b * S_LEN + s0 + s) * D_MODEL + h * DH + d8;
            f32x4 a = *(const f32x4*)p;
            f32x4 c = *(const f32x4*)(p + 4);
            #pragma unroll
            for (int j = 0; j < 4; ++j) { tsF[s][d8 + j] = a[j]; tsF[s][d8 + 4 + j] = c[j]; }
        }
        __syncthreads();
        #pragma unroll
        for (int it = 0; it < 2; ++it) {
            int seg = tid + it * 256;
            int d = seg >> 3, s8 = (seg & 7) << 3;
            short8 w;
            #pragma unroll
            for (int j = 0; j < 8; ++j) w[j] = (short)f2bf(tsF[s8 + j][d]);
            *(short8*)(VT + ((size_t)((b * 16 + h) * 64 + d)) * S_LEN + s0 + s8) = w;
        }
    } else if (blk < 2048) {
        const int pb   = blk - 1024;
        const int wave = tid >> 6, lane = tid & 63;
        const int row  = pb * 4 + wave;
        const int* mp  = M + (size_t)row * S_LEN;
        #pragma unroll 4
        for (int it = 0; it < 32; ++it) {
            int m = mp[it * 64 + lane];
            unsigned long long bal = __ballot(m != 0);
            if (lane == 0) Mb[(size_t)row * 32 + it] = bal;
        }
    } else {
        size_t base = (size_t)(blk - 2048) * 4096;
        #pragma unroll
        for (int it = 0; it < 4; ++it) {
            size_t i = base + ((size_t)(it * 256 + tid)) * 4;
            f32x4 a = *(const f32x4*)(K + i);
            s4v w;
            #pragma unroll
            for (int j = 0; j < 4; ++j) w[j] = (short)f2bf(a[j]);
            *(s4v*)(KB + i) = w;
        }
    }
}

// ---- main kernel (final) = v15, the session's best-measured configuration:
//  * sigma-permuted K staging + swapped-QK -> P stays in registers
//  * unpadded LDS rows + 16B-granule XOR swizzle -> 0 bank conflicts
//  * bias-free softmax: Q pre-scaled, p = exp2(mfma out); mask via
//    in-register nibble-spread AND on packed bf16 P-fragments
//  * fine QK/PV interleave (PV[kc] right after its two QK cts)
//  * T14 prefetch of next tile; raw s_barrier pair (no vmcnt drain)
//  * XCD-chunked block swizzle (K/V L2-resident per XCD)
__global__ __launch_bounds__(256) void mha_fwd_v15(
    const float* __restrict__ Q,
    const float* __restrict__ K,             // f32 (used when KB == 0)
    const unsigned short* __restrict__ KB,   // bf16 preconverted (may be null)
    const unsigned short* __restrict__ VT,   // bf16 pre-transposed [d][s]
    const unsigned long long* __restrict__ Mb, // packed mask u64, 32/row
    float* __restrict__ O,
    int kbf)
{
    __shared__ alignas(16) unsigned short Ks[BK][64];   // 16 KB, stride 32 dw
    __shared__ alignas(16) unsigned short Vt[DH][128];  // 16 KB, stride 64 dw

    // XCD-chunked swizzle: nwg=512, 8 XCDs -> each XCD gets 64 contiguous blk
    const int blk0 = blockIdx.x;
    const int blk  = ((blk0 & 7) << 6) | (blk0 >> 3);

    const int b   = blk >> 8;
    const int h   = (blk >> 4) & 15;
    const int qbase = (blk & 15) * BQ;
    const int bh  = b * 16 + h;

    const int tid  = threadIdx.x;
    const int wave = tid >> 6;
    const int lane = tid & 63;
    const int n16  = lane & 15;
    const int quad = lane >> 4;
    const int bq   = quad << 3;          // mask half-word shift
    const int n7   = n16 & 7;

    // K staging: 256 thr cover 32 rows x 64 cols per round (4 rounds), sigma rows
    const int srow = tid >> 3;
    const int prow = (((srow >> 2) & 1) << 4) | (((srow >> 3) & 3) << 2) | (srow & 3);
    // V staging: 256 thr cover 16 rows x 128 cols per round (4 rounds)
    const int vrow = tid >> 4;

    // LDS XOR-swizzle columns (16B granules; phys = logical ^ (row & (ng-1)))
    const int kwcol = (((tid & 7) ^ (prow & 7)) << 3);    // K write col
    const int vwcol = (((tid & 15) ^ vrow) << 3);         // V write col
    const int krc0  = ((quad ^ n7) << 3);                 // K read col, logical g=quad
    const int krc1  = krc0 ^ 32;                          // logical g=quad+4
    int vrc[4];                                           // V read col per kc
    #pragma unroll
    for (int kc = 0; kc < 4; ++kc) vrc[kc] = (((kc * 4 + quad) ^ n16) << 3);

    // Q fragments (B operand), PRE-SCALED by ZSCALE
    short8 qf[2][2];
    #pragma unroll
    for (int qg = 0; qg < 2; ++qg) {
        const size_t qoff = (size_t)(b * S_LEN + qbase + wave * 32 + qg * 16 + n16) * D_MODEL
                          + h * DH + quad * 8;
        f32x4 a0 = *(const f32x4*)(Q + qoff);
        f32x4 a1 = *(const f32x4*)(Q + qoff + 4);
        f32x4 a2 = *(const f32x4*)(Q + qoff + 32);
        f32x4 a3 = *(const f32x4*)(Q + qoff + 36);
        short8 q0, q1;
        #pragma unroll
        for (int j = 0; j < 4; ++j) {
            q0[j] = (short)f2bf(a0[j] * ZSCALE); q0[4 + j] = (short)f2bf(a1[j] * ZSCALE);
            q1[j] = (short)f2bf(a2[j] * ZSCALE); q1[4 + j] = (short)f2bf(a3[j] * ZSCALE);
        }
        qf[qg][0] = q0; qf[qg][1] = q1;
    }

    const short8 ones = {0x3F80,0x3F80,0x3F80,0x3F80,0x3F80,0x3F80,0x3F80,0x3F80}; // bf16 1.0

    f32x4 o[2][4], o4[2];
    #pragma unroll
    for (int qg = 0; qg < 2; ++qg) {
        #pragma unroll
        for (int dg = 0; dg < 4; ++dg) o[qg][dg] = f32x4{0.f,0.f,0.f,0.f};
        o4[qg] = f32x4{0.f,0.f,0.f,0.f};
    }

    const unsigned long long* mrow[2];
    #pragma unroll
    for (int qg = 0; qg < 2; ++qg)
        mrow[qg] = Mb + (size_t)(b * S_LEN + qbase + wave * 32 + qg * 16 + n16) * 32;

    const size_t kbase = (size_t)(b * S_LEN) * D_MODEL + h * DH;
    const size_t vbase = (size_t)(bh * 64) * S_LEN;

    // ---- prologue: prefetch tile 0 into regs ----
    short8 ka[4], va[4];
    unsigned long long mw[2][2];
    if (kbf) {
        #pragma unroll
        for (int i = 0; i < 4; ++i)
            ka[i] = *(const short8*)(KB + kbase + (size_t)(i * 32 + srow) * D_MODEL + ((tid & 7) << 3));
    } else {
        #pragma unroll
        for (int i = 0; i < 4; ++i) {
            const float* kp = K + kbase + (size_t)(i * 32 + srow) * D_MODEL + ((tid & 7) << 3);
            f32x4 p0 = *(const f32x4*)kp, p1 = *(const f32x4*)(kp + 4);
            short8 w;
            #pragma unroll
            for (int j = 0; j < 4; ++j) { w[j] = (short)f2bf(p0[j]); w[4 + j] = (short)f2bf(p1[j]); }
            ka[i] = w;
        }
    }
    #pragma unroll
    for (int i = 0; i < 4; ++i)   // VT is [d][s]: tile offset on the COLUMN
        va[i] = *(const short8*)(VT + vbase + (size_t)(vrow + 16 * i) * S_LEN + ((tid & 15) << 3));
    #pragma unroll
    for (int qg = 0; qg < 2; ++qg) { mw[qg][0] = mrow[qg][0]; mw[qg][1] = mrow[qg][1]; }

    for (int kb = 0; kb < S_LEN; kb += BK) {
        // barrier 1: all waves done READING prev tile; raw (no vmcnt drain)
        __builtin_amdgcn_s_barrier();
        __builtin_amdgcn_sched_barrier(0);

        // stage tile (swizzled columns; sigma-permuted K rows)
        #pragma unroll
        for (int i = 0; i < 4; ++i) {
            *(short8*)&Ks[prow + 32 * i][kwcol] = ka[i];
            *(short8*)&Vt[vrow + 16 * i][vwcol] = va[i];
        }

        // issue next tile's loads — consumed by NEXT iteration's ds_writes
        const int kn = kb + BK;
        const bool more = kn < S_LEN;
        short8 nka[4], nva[4];
        unsigned long long nmw[2][2];
        if (more) {
            if (kbf) {
                #pragma unroll
                for (int i = 0; i < 4; ++i)
                    nka[i] = *(const short8*)(KB + kbase + (size_t)(kn + i * 32 + srow) * D_MODEL + ((tid & 7) << 3));
            } else {
                #pragma unroll
                for (int i = 0; i < 4; ++i) {
                    const float* kp = K + kbase + (size_t)(kn + i * 32 + srow) * D_MODEL + ((tid & 7) << 3);
                    f32x4 p0 = *(const f32x4*)kp, p1 = *(const f32x4*)(kp + 4);
                    short8 w;
                    #pragma unroll
                    for (int j = 0; j < 4; ++j) { w[j] = (short)f2bf(p0[j]); w[4 + j] = (short)f2bf(p1[j]); }
                    nka[i] = w;
                }
            }
            #pragma unroll
            for (int i = 0; i < 4; ++i)
                nva[i] = *(const short8*)(VT + vbase + (size_t)(vrow + 16 * i) * S_LEN + kn + ((tid & 15) << 3));
            const int wi = kn >> 6;
            #pragma unroll
            for (int qg = 0; qg < 2; ++qg) { nmw[qg][0] = mrow[qg][wi]; nmw[qg][1] = mrow[qg][wi + 1]; }
        }

        // mask half-words (register-only; hoisted off the post-barrier path)
        unsigned int am[2][4];
        #pragma unroll
        for (int qg = 0; qg < 2; ++qg) {
            am[qg][0] = ((unsigned int)mw[qg][0]) >> bq;
            am[qg][1] = ((unsigned int)(mw[qg][0] >> 32)) >> bq;
            am[qg][2] = ((unsigned int)mw[qg][1]) >> bq;
            am[qg][3] = ((unsigned int)(mw[qg][1] >> 32)) >> bq;
        }

        // barrier 2: my LDS writes committed (lgkm only), then all waves sync
        asm volatile("s_waitcnt lgkmcnt(0)" ::: "memory");
        __builtin_amdgcn_s_barrier();
        __builtin_amdgcn_sched_barrier(0);

        // ---- interleaved compute: PV[kc] fires right after its two QK cts ----
        u32x4 Af[2][4];   // [qg][kc]
        auto QKCT = [&](int ct) {
            short8 kf0 = *(const short8*)&Ks[ct * 16 + n16][krc0];
            short8 kf1 = *(const short8*)&Ks[ct * 16 + n16][krc1];
            f32x4 sA = {0.f,0.f,0.f,0.f}, sB = sA;
            sA = BMM(kf0, qf[0][0], sA); sA = BMM(kf1, qf[0][1], sA);
            sB = BMM(kf0, qf[1][0], sB); sB = BMM(kf1, qf[1][1], sB);
            unsigned int puA[4], puB[4];
            #pragma unroll
            for (int r = 0; r < 4; ++r) {
                puA[r] = __float_as_uint(__builtin_amdgcn_exp2f(sA[r]));
                puB[r] = __float_as_uint(__builtin_amdgcn_exp2f(sB[r]));
            }
            const int sel = ct >> 1, sb = (ct & 1) * 4, kc = ct >> 1, ub = (ct & 1) * 2;
            unsigned int nibA = (am[0][sel] >> sb) & 0xFu;
            unsigned int nibB = (am[1][sel] >> sb) & 0xFu;
            unsigned int m8A = ((nibA * 0x00204081u) & 0x01010101u) * 0xFFu;
            unsigned int m8B = ((nibB * 0x00204081u) & 0x01010101u) * 0xFFu;
            Af[0][kc][ub + 0] = __builtin_amdgcn_perm(puA[1], puA[0], 0x07060302u)
                              & __builtin_amdgcn_perm(0u, m8A, 0x01010000u);
            Af[0][kc][ub + 1] = __builtin_amdgcn_perm(puA[3], puA[2], 0x07060302u)
                              & __builtin_amdgcn_perm(0u, m8A, 0x03030202u);
            Af[1][kc][ub + 0] = __builtin_amdgcn_perm(puB[1], puB[0], 0x07060302u)
                              & __builtin_amdgcn_perm(0u, m8B, 0x01010000u);
            Af[1][kc][ub + 1] = __builtin_amdgcn_perm(puB[3], puB[2], 0x07060302u)
                              & __builtin_amdgcn_perm(0u, m8B, 0x03030202u);
        };
        auto PVKC = [&](int kc) {
            short8 v0 = *(const short8*)&Vt[      n16][vrc[kc]];
            short8 v1 = *(const short8*)&Vt[16 + n16][vrc[kc]];
            short8 v2 = *(const short8*)&Vt[32 + n16][vrc[kc]];
            short8 v3 = *(const short8*)&Vt[48 + n16][vrc[kc]];
            union { u32x4 u; short8 s; } c0, c1;
            c0.u = Af[0][kc]; c1.u = Af[1][kc];
            o[0][0] = BMM(c0.s, v0, o[0][0]); o[0][1] = BMM(c0.s, v1, o[0][1]);
            o[0][2] = BMM(c0.s, v2, o[0][2]); o[0][3] = BMM(c0.s, v3, o[0][3]);
            o4[0]   = BMM(c0.s, ones, o4[0]);
            o[1][0] = BMM(c1.s, v0, o[1][0]); o[1][1] = BMM(c1.s, v1, o[1][1]);
            o[1][2] = BMM(c1.s, v2, o[1][2]); o[1][3] = BMM(c1.s, v3, o[1][3]);
            o4[1]   = BMM(c1.s, ones, o4[1]);
        };

        __builtin_amdgcn_s_setprio(1);
        QKCT(0); QKCT(1);
        PVKC(0);
        QKCT(2); QKCT(3);
        PVKC(1);
        QKCT(4); QKCT(5);
        PVKC(2);
        QKCT(6); QKCT(7);
        PVKC(3);
        __builtin_amdgcn_s_setprio(0);

        if (more) {
            #pragma unroll
            for (int i = 0; i < 4; ++i) { ka[i] = nka[i]; va[i] = nva[i]; }
            #pragma unroll
            for (int qg = 0; qg < 2; ++qg) { mw[qg][0] = nmw[qg][0]; mw[qg][1] = nmw[qg][1]; }
        }
    }

    // epilogue: normalize by MFMA row sums, store f32 (row=quad*4+r, col=n16)
    #pragma unroll
    for (int qg = 0; qg < 2; ++qg) {
        #pragma unroll
        for (int r = 0; r < 4; ++r) {
            float rl = 1.f / o4[qg][r];
            size_t row = (size_t)(b * S_LEN + qbase + wave * 32 + qg * 16 + quad * 4 + r);
            float* op = O + row * D_MODEL + h * DH + n16;
            op[0]  = o[qg][0][r] * rl;
            op[16] = o[qg][1][r] * rl;
            op[32] = o[qg][2][r] * rl;
            op[48] = o[qg][3][r] * rl;
        }
    }
}

extern "C" void kernel_launch(void* const* d_in, const int* in_sizes, int n_in,
                              void* d_out, int out_size, void* d_ws, size_t ws_size,
                              hipStream_t stream) {
    const float* Q = (const float*)d_in[0];
    const float* K = (const float*)d_in[1];
    const float* V = (const float*)d_in[2];
    const int*   M = (const int*)d_in[3];
    float*       O = (float*)d_out;

    const size_t NEL = (size_t)2 * S_LEN * D_MODEL;            // 4,194,304
    const size_t VT_BYTES = NEL * sizeof(unsigned short);      // 8 MB
    const size_t KB_BYTES = NEL * sizeof(unsigned short);      // 8 MB
    const size_t MB_BYTES = (size_t)2 * S_LEN * 32 * 8;        // 1 MB

    if (ws_size >= VT_BYTES + KB_BYTES + MB_BYTES) {           // 17 MB: full precompute
        unsigned short* VT = (unsigned short*)d_ws;
        unsigned short* KB = (unsigned short*)((char*)d_ws + VT_BYTES);
        unsigned long long* Mb = (unsigned long long*)((char*)d_ws + VT_BYTES + KB_BYTES);
        hipLaunchKernelGGL(cvt_fused, dim3(3072), dim3(256), 0, stream, V, M, K, VT, Mb, KB);
        hipLaunchKernelGGL(mha_fwd_v15, dim3(512), dim3(256), 0, stream,
                           Q, K, KB, VT, Mb, O, 1);
    } else {                                                   // 9 MB: inline K convert
        unsigned short* VT = (unsigned short*)d_ws;
        unsigned long long* Mb = (unsigned long long*)((char*)d_ws + VT_BYTES);
        hipLaunchKernelGGL(cvt_fused, dim3(2048), dim3(256), 0, stream, V, M, K, VT, Mb, (unsigned short*)0);
        hipLaunchKernelGGL(mha_fwd_v15, dim3(512), dim3(256), 0, stream,
                           Q, K, (const unsigned short*)0, VT, Mb, O, 0);
    }
}